// Round 13
// baseline (334.400 us; speedup 1.0000x reference)
//
#include <hip/hip_runtime.h>
#include <math.h>

#define N_TOK 32768
#define DIM   256
#define KCODE 4096

// ---- workspace layout (float offsets) ----
#define WS_E2      0                      // [4096]
#define WS_COUNTS  4096                   // [4096]
#define WS_LOSSP   8192                   // [256]
#define WS_SCAL    8448                   // [64]  scal[0]=bias
#define WS_CNORM   8512                   // [4096]
#define WS_IDX     12608                  // int [32768]
#define WS_EHS     307520                 // fp16 planes [2][16][8][256][32] = 4 MB
#define WS_DWT     1356096                // dwT [4096*256]
#define WS_CARRYV  2404672                // float [32768] carry best value / later rowlist
#define WS_CARRYI  2437440                // int   [32768] carry best index
#define WS_OFFS    2470208                // int [4096] bucket starts
#define WS_WOFF    2474304                // int [4096] scatter cursors

// ---- output layout (float offsets) ----
#define OUT_Q      0
#define OUT_LOSS   8388608
#define OUT_PERP   8388609
#define OUT_IDX    8388610
#define OUT_EMB    8421378

#define EH_PLANE   1048576                // halves per eh plane

typedef _Float16 f16x8 __attribute__((ext_vector_type(8)));
typedef _Float16 f16x4 __attribute__((ext_vector_type(4)));
typedef float    f32x4 __attribute__((ext_vector_type(4)));

// emb [D][K] -> pre-tiled split planes ehs[p][ct][ks][code&255][d&31]
// ALSO accumulates e2[k] = sum_d emb[d][k]^2 (e2 pre-zeroed).
__global__ void k_split_e(const float* __restrict__ emb, unsigned short* __restrict__ ehs_,
                          float* __restrict__ e2)
{
    __shared__ float tile[32][33];
    _Float16* ehs = (_Float16*)ehs_;
    int t  = threadIdx.x;
    int tx = t & 31, iy = t >> 5;
    int k0 = blockIdx.x * 32, d0 = blockIdx.y * 32;
#pragma unroll
    for (int j = 0; j < 4; ++j)
        tile[iy + 8 * j][tx] = emb[(size_t)(d0 + iy + 8 * j) * KCODE + k0 + tx];
    __syncthreads();
    int code = k0 + tx;
    size_t base = (size_t)(((code >> 8) * 8) + (d0 >> 5)) * 8192 + (code & 255) * 32 + iy * 4;
    f16x4 h1, h2;
    float ssq = 0.0f;
#pragma unroll
    for (int j = 0; j < 4; ++j) {
        float v = tile[iy * 4 + j][tx];
        ssq += v * v;
        _Float16 a = (_Float16)v;
        h1[j] = a;
        h2[j] = (_Float16)(v - (float)a);
    }
    *(f16x4*)(ehs + base)            = h1;
    *(f16x4*)(ehs + EH_PLANE + base) = h2;
    atomicAdd(&e2[code], ssq);
}

// Argmin via fp16x2-split MFMA, two ct-half dispatches (2 MB L2 WS each).
// MFMA core = the round-10 body (best measured: 100us, 124 VGPR, no spills).
// Six schedule variants all plateaued at ~100us/45% MfmaUtil -> structurally
// latency-bound at 2 waves/SIMD; schedule work stopped.
// NEW (tail surgery): phase-B epilogue emits loss and out_q directly.
//   loss_row = bv + ||x_row||^2   (bv = e2 - 2*dot IS the winning distance)
//   out_q[row] = reconstruct(ehs[bi])  -- 64KB/block coalesced, ehs L2-hot.
// ||x||^2 partials come free during A-staging (xsqp, 2KB LDS).
__global__ __launch_bounds__(256, 2)
void k_argmin(const float* __restrict__ x, const unsigned short* __restrict__ ehs_,
              const float* __restrict__ e2, int* __restrict__ idx_out,
              float* __restrict__ carryV, int* __restrict__ carryI,
              float* __restrict__ out_idxf, float* __restrict__ counts,
              float* __restrict__ lossp, float* __restrict__ out_q,
              int ct0, int phase)
{
    __shared__ __align__(16) _Float16 Ah[2][64][256];   // 64 KB; XOR-swizzled 8-elem groups
    __shared__ float xsqp[64][8];                       // ||x||^2 partials
    __shared__ int   bis[64];                           // winning code per row (phase B)

    const _Float16* ehs = (const _Float16*)ehs_;

    const int t    = threadIdx.x;
    const int lane = t & 63, w = t >> 6;
    const int lo   = lane & 15, q = lane >> 4;
    const int row0 = blockIdx.x * 64;

    // ---- prologue: stage A planes from x with on-the-fly fp16 split ----
    {
        int m = t >> 3, kb = (t & 7) * 32;
        float ssq0 = 0.0f, ssq1 = 0.0f;
#pragma unroll
        for (int rr = 0; rr < 2; ++rr) {
            int mm = m + 32 * rr;
            const float* src = x + (size_t)(row0 + mm) * DIM + kb;
            float ss = 0.0f;
#pragma unroll
            for (int g = 0; g < 4; ++g) {
                f32x4 f0 = __builtin_nontemporal_load((const f32x4*)(src + g * 8));
                f32x4 f1 = __builtin_nontemporal_load((const f32x4*)(src + g * 8 + 4));
                f16x8 h1, h2;
#pragma unroll
                for (int j = 0; j < 4; ++j) {
                    ss += f0[j] * f0[j] + f1[j] * f1[j];
                    _Float16 a = (_Float16)f0[j];
                    h1[j] = a; h2[j] = (_Float16)(f0[j] - (float)a);
                    _Float16 b = (_Float16)f1[j];
                    h1[j + 4] = b; h2[j + 4] = (_Float16)(f1[j] - (float)b);
                }
                int grp = ((kb >> 3) + g) ^ (mm & 7);
                *(f16x8*)&Ah[0][mm][grp * 8] = h1;
                *(f16x8*)&Ah[1][mm][grp * 8] = h2;
            }
            if (rr == 0) ssq0 = ss; else ssq1 = ss;
        }
        xsqp[m][t & 7]      = ssq0;
        xsqp[m + 32][t & 7] = ssq1;
    }
    __syncthreads();   // the ONLY barrier before the epilogue

    float best[16];
    int   bidx[16];
#pragma unroll
    for (int s = 0; s < 16; ++s) { best[s] = 3.4e38f; bidx[s] = 0x40000000; }

    // B fragment base: code-within-tile crow = w*64 + nf*16 + lo, d-off q*8
    const _Float16* ehp1 = ehs + (size_t)(w * 64 + lo) * 32 + q * 8;
    const _Float16* ehp2 = ehp1 + EH_PLANE;

    // register double-buffer for B fragments; parity = ks&1 (ks fully unrolled)
    f16x8 b1f[2][4], b2f[2][4];

    // prime: load B for so = ct0*8
    {
        const size_t so0 = (size_t)(ct0 * 8) * 8192;
#pragma unroll
        for (int nf = 0; nf < 4; ++nf) {
            b1f[0][nf] = *(const f16x8*)(ehp1 + so0 + nf * 512);
            b2f[0][nf] = *(const f16x8*)(ehp2 + so0 + nf * 512);
        }
    }

    for (int ct = ct0; ct < ct0 + 8; ++ct) {
        // prefetch this ct's e2 values (used only in the fold)
        float e2r[4];
#pragma unroll
        for (int nf = 0; nf < 4; ++nf)
            e2r[nf] = e2[ct * 256 + w * 64 + nf * 16 + lo];

        f32x4 acc[4][4];
#pragma unroll
        for (int mf = 0; mf < 4; ++mf)
#pragma unroll
            for (int nf = 0; nf < 4; ++nf) acc[mf][nf] = (f32x4)0.0f;

#pragma unroll
        for (int ks = 0; ks < 8; ++ks) {
            const int cur = ks & 1, nxt = cur ^ 1;
            const int so  = ct * 8 + ks;

            // ---- prefetch B for so+1 into the other parity buffer ----
            if (ks < 7 || ct < ct0 + 7) {
                const size_t po = (size_t)(so + 1) * 8192;
#pragma unroll
                for (int nf = 0; nf < 4; ++nf) {
                    b1f[nxt][nf] = *(const f16x8*)(ehp1 + po + nf * 512);
                    b2f[nxt][nf] = *(const f16x8*)(ehp2 + po + nf * 512);
                }
            }
            // pin the prefetch ahead of the MFMA cluster
            __builtin_amdgcn_sched_barrier(0);

            // ---- A fragments via LDS (conflict-free b128 via XOR swizzle) ----
            const int agrp = ((ks * 4 + q) ^ (lo & 7)) * 8;
            f16x8 a1[4], a2[4];
#pragma unroll
            for (int mf = 0; mf < 4; ++mf)
                a2[mf] = *(const f16x8*)&Ah[1][mf * 16 + lo][agrp];
#pragma unroll
            for (int mf = 0; mf < 4; ++mf)
                a1[mf] = *(const f16x8*)&Ah[0][mf * 16 + lo][agrp];

            // ---- MFMA cluster: per nf, product-major across mf (reuse dist 4) ----
#pragma unroll
            for (int nf = 0; nf < 4; ++nf) {
#pragma unroll
                for (int mf = 0; mf < 4; ++mf)
                    acc[mf][nf] = __builtin_amdgcn_mfma_f32_16x16x32_f16(a2[mf], b1f[cur][nf], acc[mf][nf], 0, 0, 0);
#pragma unroll
                for (int mf = 0; mf < 4; ++mf)
                    acc[mf][nf] = __builtin_amdgcn_mfma_f32_16x16x32_f16(a1[mf], b2f[cur][nf], acc[mf][nf], 0, 0, 0);
#pragma unroll
                for (int mf = 0; mf < 4; ++mf)
                    acc[mf][nf] = __builtin_amdgcn_mfma_f32_16x16x32_f16(a1[mf], b1f[cur][nf], acc[mf][nf], 0, 0, 0);
            }
        }

        // fold: dist = e2 - 2*score; exact lowest-index tie-break.
#pragma unroll
        for (int nf = 0; nf < 4; ++nf) {
            int ci = ct * 256 + w * 64 + nf * 16 + lo;
            float e2v = e2r[nf];
#pragma unroll
            for (int mf = 0; mf < 4; ++mf)
#pragma unroll
                for (int r = 0; r < 4; ++r) {
                    float dist = fmaf(-2.0f, acc[mf][nf][r], e2v);
                    int s = mf * 4 + r;
                    if (dist < best[s] || (dist == best[s] && ci < bidx[s])) {
                        best[s] = dist; bidx[s] = ci;
                    }
                }
        }
    }

    // ---- final argmin reduction (scratch overlays Ah) ----
    __syncthreads();
    float* rv = (float*)&Ah[0][0][0];                 // [64 rows][64 slots]
    int*   ri = (int*)(((char*)&Ah[0][0][0]) + 16384);
#pragma unroll
    for (int s = 0; s < 16; ++s) {
        int row = (s >> 2) * 16 + q * 4 + (s & 3);    // mf*16 + q*4 + r
        rv[row * 64 + w * 16 + lo] = best[s];
        ri[row * 64 + w * 16 + lo] = bidx[s];
    }
    __syncthreads();
    if (t < 64) {
        float bv; int bi;
        if (phase) { bv = carryV[row0 + t]; bi = carryI[row0 + t]; }
        else       { bv = 3.4e38f; bi = 0x40000000; }
        // staggered scan start -> conflict-free
        for (int jj = 0; jj < 64; ++jj) {
            int j = (jj + t) & 63;
            float v = rv[t * 64 + j];
            int  ii = ri[t * 64 + j];
            if (v < bv || (v == bv && ii < bi)) { bv = v; bi = ii; }
        }
        if (phase) {
            idx_out[row0 + t] = bi;
            out_idxf[row0 + t] = (float)bi;
            atomicAdd(&counts[bi], 1.0f);
            bis[t] = bi;
            // loss_row = winning distance + ||x_row||^2
            float xsq = 0.0f;
#pragma unroll
            for (int j = 0; j < 8; ++j) xsq += xsqp[t][j];
            float lr = bv + xsq;
#pragma unroll
            for (int off = 32; off > 0; off >>= 1) lr += __shfl_down(lr, off, 64);
            if (t == 0) atomicAdd(&lossp[blockIdx.x & 255], lr);
        } else {
            carryV[row0 + t] = bv; carryI[row0 + t] = bi;
        }
    }
    // ---- phase B: write quantized rows from ehs (L2-hot) ----
    if (phase) {
        __syncthreads();
        int r  = t >> 2, qs = t & 3;       // 4 threads per row, 64 dims each
        int k  = bis[r];
        float* dst = out_q + (size_t)(row0 + r) * DIM + qs * 64;
        const _Float16* ehb = ehs + (size_t)((k >> 8) * 8 + qs * 2) * 8192 + (k & 255) * 32;
#pragma unroll
        for (int dd = 0; dd < 2; ++dd) {
            const _Float16* p1 = ehb + dd * 8192;
            const _Float16* p2 = p1 + EH_PLANE;
#pragma unroll
            for (int g = 0; g < 4; ++g) {
                f16x8 h1 = *(const f16x8*)(p1 + g * 8);
                f16x8 h2 = *(const f16x8*)(p2 + g * 8);
                float4 o0, o1;
                o0.x = (float)h1[0] + (float)h2[0];
                o0.y = (float)h1[1] + (float)h2[1];
                o0.z = (float)h1[2] + (float)h2[2];
                o0.w = (float)h1[3] + (float)h2[3];
                o1.x = (float)h1[4] + (float)h2[4];
                o1.y = (float)h1[5] + (float)h2[5];
                o1.z = (float)h1[6] + (float)h2[6];
                o1.w = (float)h1[7] + (float)h2[7];
                *(float4*)(dst + dd * 32 + g * 8)     = o0;
                *(float4*)(dst + dd * 32 + g * 8 + 4) = o1;
            }
        }
    }
}

// merged: exclusive prefix sum over counts -> offs/woff  +  finalize
// (lossp is complete after argmin phase B, so both fit in one 1-block kernel)
__global__ void k_scanfin(const float* __restrict__ counts, const float* __restrict__ lossp,
                          const float* __restrict__ ema_counter,
                          const float* __restrict__ ema_cluster,
                          int* __restrict__ offs, int* __restrict__ woff,
                          float* __restrict__ cnorm, float* __restrict__ scal,
                          float* __restrict__ out)
{
    __shared__ int   ps[256];
    __shared__ float red[256];
    int t = threadIdx.x;

    // ---- scan ----
    int local[16];
    int s = 0;
#pragma unroll
    for (int j = 0; j < 16; ++j) {
        local[j] = s;
        s += (int)counts[t * 16 + j];
    }
    ps[t] = s;
    __syncthreads();
    for (int off = 1; off < 256; off <<= 1) {
        int v = (t >= off) ? ps[t - off] : 0;
        __syncthreads();
        ps[t] += v;
        __syncthreads();
    }
    int base = (t > 0) ? ps[t - 1] : 0;
#pragma unroll
    for (int j = 0; j < 16; ++j) {
        int o = base + local[j];
        offs[t * 16 + j] = o;
        woff[t * 16 + j] = o;
    }

    // ---- finalize ----
    float ls = lossp[t];
    float ent = 0.0f, casum = 0.0f;
    float ca[16];
#pragma unroll
    for (int j = 0; j < 16; ++j) {
        int k = j * 256 + t;
        float c = counts[k];
        float p = c * (1.0f / 32768.0f);
        ent += p * logf(p + 1e-10f);
        ca[j] = ema_cluster[k] * 0.99f + c * 0.01f;
        casum += ca[j];
    }
    __syncthreads();
    red[t] = ls; __syncthreads();
    for (int o = 128; o > 0; o >>= 1) { if (t < o) red[t] += red[t + o]; __syncthreads(); }
    float loss_tot = red[0]; __syncthreads();
    red[t] = ent; __syncthreads();
    for (int o = 128; o > 0; o >>= 1) { if (t < o) red[t] += red[t + o]; __syncthreads(); }
    float ent_tot = red[0]; __syncthreads();
    red[t] = casum; __syncthreads();
    for (int o = 128; o > 0; o >>= 1) { if (t < o) red[t] += red[t + o]; __syncthreads(); }
    float casum_tot = red[0]; __syncthreads();

    float bias = 1.0f - powf(0.99f, ema_counter[0] + 1.0f);
    float n = casum_tot / bias;
    float inv = n / (n + 4096.0f * 1e-5f);
#pragma unroll
    for (int j = 0; j < 16; ++j) {
        int k = j * 256 + t;
        cnorm[k] = (ca[j] / bias + 1e-5f) * inv;
    }
    if (t == 0) {
        out[OUT_LOSS] = 1.25f * loss_tot * (1.0f / (32768.0f * 256.0f));
        out[OUT_PERP] = expf(-ent_tot);
        scal[0] = bias;
    }
}

// rowlist[pos] = n, grouped by code (counting-sort scatter)
__global__ void k_scatter(const int* __restrict__ idx, int* __restrict__ woff,
                          int* __restrict__ rowlist)
{
    int n = blockIdx.x * 256 + threadIdx.x;
    int k = idx[n];
    int pos = atomicAdd(&woff[k], 1);
    rowlist[pos] = n;
}

// dwT[k][:] = sum of x rows in bucket k — pure, no atomics, no loss, no out_q
__global__ void k_dw(const float* __restrict__ x, const int* __restrict__ rowlist,
                     const int* __restrict__ offs, const float* __restrict__ counts,
                     float* __restrict__ dwT)
{
    __shared__ __align__(16) float red[4][256];
    int k = blockIdx.x, t = threadIdx.x;
    int lane = t & 63, w = t >> 6;
    int start = offs[k];
    int cnt   = (int)counts[k];
    float4 acc = {0.0f, 0.0f, 0.0f, 0.0f};
    for (int j = w; j < cnt; j += 4) {
        int n = rowlist[start + j];
        float4 xv = *(const float4*)&x[(size_t)n * DIM + lane * 4];
        acc.x += xv.x; acc.y += xv.y; acc.z += xv.z; acc.w += xv.w;
    }
    *(float4*)&red[w][lane * 4] = acc;
    __syncthreads();
    float s = red[0][t] + red[1][t] + red[2][t] + red[3][t];
    dwT[(size_t)k * DIM + t] = s;
}

// new_embeddings[d][k] = (ema_dw*DECAY + dwT^T*(1-DECAY))/bias / cnorm[k]
__global__ void k_newemb(const float* __restrict__ dwT, const float* __restrict__ ema_dw,
                         const float* __restrict__ cnorm, const float* __restrict__ scal,
                         float* __restrict__ out_emb)
{
    __shared__ float tile[32][33];
    int t = threadIdx.x;
    int tx = t & 31, iy = t >> 5;
    int k0 = blockIdx.x * 32, d0 = blockIdx.y * 32;
#pragma unroll
    for (int j = 0; j < 4; ++j)
        tile[iy + 8 * j][tx] = dwT[(size_t)(k0 + iy + 8 * j) * DIM + d0 + tx];
    __syncthreads();
    float inv_bias = 1.0f / scal[0];
    float cn = cnorm[k0 + tx];
#pragma unroll
    for (int j = 0; j < 4; ++j) {
        int d = d0 + iy + 8 * j;
        float dwv = tile[tx][iy + 8 * j];
        float hid = ema_dw[(size_t)d * KCODE + k0 + tx] * 0.99f + dwv * 0.01f;
        out_emb[(size_t)d * KCODE + k0 + tx] = hid * inv_bias / cn;
    }
}

extern "C" void kernel_launch(void* const* d_in, const int* in_sizes, int n_in,
                              void* d_out, int out_size, void* d_ws, size_t ws_size,
                              hipStream_t stream)
{
    const float* x           = (const float*)d_in[0];
    const float* emb         = (const float*)d_in[1];
    const float* ema_counter = (const float*)d_in[2];
    const float* ema_cluster = (const float*)d_in[3];
    const float* ema_dw      = (const float*)d_in[4];
    float* out = (float*)d_out;
    float* ws  = (float*)d_ws;

    float* e2     = ws + WS_E2;
    float* counts = ws + WS_COUNTS;
    float* lossp  = ws + WS_LOSSP;
    float* scal   = ws + WS_SCAL;
    float* cnorm  = ws + WS_CNORM;
    int*   idxw   = (int*)(ws + WS_IDX);
    unsigned short* ehs = (unsigned short*)(ws + WS_EHS);
    float* dwT    = ws + WS_DWT;
    float* carryV = ws + WS_CARRYV;
    int*   carryI = (int*)(ws + WS_CARRYI);
    int*   rowlist= (int*)(ws + WS_CARRYV);   // overlays carryV (dead after argmin B)
    int*   offs   = (int*)(ws + WS_OFFS);
    int*   woff   = (int*)(ws + WS_WOFF);

    hipMemsetAsync(e2, 0, (size_t)WS_CNORM * sizeof(float), stream);  // zeros e2+counts+lossp+scal

    k_split_e<<<dim3(128, 8), 256, 0, stream>>>(emb, ehs, e2);
    // two ct-half dispatches (round-10 schedule); phase B also emits loss+out_q
    k_argmin<<<512, 256, 0, stream>>>(x, ehs, e2, idxw, carryV, carryI,
                                      out + OUT_IDX, counts, lossp, out + OUT_Q, 0, 0);
    k_argmin<<<512, 256, 0, stream>>>(x, ehs, e2, idxw, carryV, carryI,
                                      out + OUT_IDX, counts, lossp, out + OUT_Q, 8, 1);
    // merged scan+finalize (1 block) -> scatter -> pure-dwT -> newemb
    k_scanfin<<<1, 256, 0, stream>>>(counts, lossp, ema_counter, ema_cluster,
                                     offs, woff, cnorm, scal, out);
    k_scatter<<<128, 256, 0, stream>>>(idxw, woff, rowlist);
    k_dw<<<4096, 256, 0, stream>>>(x, rowlist, offs, counts, dwT);
    k_newemb<<<dim3(128, 8), 256, 0, stream>>>(dwT, ema_dw, cnorm, scal, out + OUT_EMB);
}

// Round 14
// 326.562 us; speedup vs baseline: 1.0240x; 1.0240x over previous
//
#include <hip/hip_runtime.h>
#include <math.h>

#define N_TOK 32768
#define DIM   256
#define KCODE 4096

// ---- workspace layout (float offsets) ----
#define WS_E2      0                      // [4096]
#define WS_COUNTS  4096                   // [4096]
#define WS_LOSSP   8192                   // [256]
#define WS_SCAL    8448                   // [64]  scal[0]=bias
#define WS_CNORM   8512                   // [4096]
#define WS_IDX     12608                  // int [32768]
#define WS_EHS     307520                 // fp16 planes [2][16][8][256][32] = 4 MB
#define WS_DWT     1356096                // dwT [4096*256]
#define WS_CARRYV  2404672                // float [32768] carry best value / later rowlist
#define WS_CARRYI  2437440                // int   [32768] carry best index
#define WS_OFFS    2470208                // int [4096] bucket starts
#define WS_WOFF    2474304                // int [4096] scatter cursors

// ---- output layout (float offsets) ----
#define OUT_Q      0
#define OUT_LOSS   8388608
#define OUT_PERP   8388609
#define OUT_IDX    8388610
#define OUT_EMB    8421378

#define EH_PLANE   1048576                // halves per eh plane

typedef _Float16 f16x8 __attribute__((ext_vector_type(8)));
typedef _Float16 f16x4 __attribute__((ext_vector_type(4)));
typedef float    f32x4 __attribute__((ext_vector_type(4)));

// emb [D][K] -> pre-tiled split planes ehs[p][ct][ks][code&255][d&31]
// Restructured: 128 blocks, each owns 32 codes FULLY (loops all 8 d-tiles)
// -> e2[k] computed exactly in-block, written ONCE (no atomics, no memset).
__global__ void k_split_e(const float* __restrict__ emb, unsigned short* __restrict__ ehs_,
                          float* __restrict__ e2)
{
    __shared__ float tile[32][33];
    __shared__ float ssq_red[8][32];
    _Float16* ehs = (_Float16*)ehs_;
    int t  = threadIdx.x;
    int tx = t & 31, iy = t >> 5;
    int k0 = blockIdx.x * 32;
    float ssq = 0.0f;
    for (int dt = 0; dt < 8; ++dt) {
        int d0 = dt * 32;
        __syncthreads();   // protect tile reuse across iterations
#pragma unroll
        for (int j = 0; j < 4; ++j)
            tile[iy + 8 * j][tx] = emb[(size_t)(d0 + iy + 8 * j) * KCODE + k0 + tx];
        __syncthreads();
        int code = k0 + tx;
        size_t base = (size_t)(((code >> 8) * 8) + (d0 >> 5)) * 8192 + (code & 255) * 32 + iy * 4;
        f16x4 h1, h2;
#pragma unroll
        for (int j = 0; j < 4; ++j) {
            float v = tile[iy * 4 + j][tx];
            ssq += v * v;
            _Float16 a = (_Float16)v;
            h1[j] = a;
            h2[j] = (_Float16)(v - (float)a);
        }
        *(f16x4*)(ehs + base)            = h1;
        *(f16x4*)(ehs + EH_PLANE + base) = h2;
    }
    ssq_red[iy][tx] = ssq;
    __syncthreads();
    if (iy == 0) {
        float s = 0.0f;
#pragma unroll
        for (int j = 0; j < 8; ++j) s += ssq_red[j][tx];
        e2[k0 + tx] = s;
    }
}

// Argmin via fp16x2-split MFMA, two ct-half dispatches (2 MB L2 WS each).
// MFMA core = round-10 body (best measured: 100us, 124 VGPR, no spills).
// Phase A additionally zeros counts/lossp (blocks 0..16) — replaces the memset
// dispatch; dispatch boundary orders the zeroing before phase B's atomics.
// Phase B epilogue emits the loss for free: loss_row = bv + ||x_row||^2
// (bv IS the winning distance; ||x||^2 partials collected during A-staging).
// out_q stays in k_dw (round 13: bundling it here cost +15us serial epilogue).
__global__ __launch_bounds__(256, 2)
void k_argmin(const float* __restrict__ x, const unsigned short* __restrict__ ehs_,
              const float* __restrict__ e2, int* __restrict__ idx_out,
              float* __restrict__ carryV, int* __restrict__ carryI,
              float* __restrict__ out_idxf, float* __restrict__ counts,
              float* __restrict__ lossp, int ct0, int phase)
{
    __shared__ __align__(16) _Float16 Ah[2][64][256];   // 64 KB; XOR-swizzled 8-elem groups
    __shared__ float xsqp[64][8];                       // ||x||^2 partials

    const _Float16* ehs = (const _Float16*)ehs_;

    const int t    = threadIdx.x;
    const int lane = t & 63, w = t >> 6;
    const int lo   = lane & 15, q = lane >> 4;
    const int row0 = blockIdx.x * 64;

    // ---- phase-A side duty: zero counts/lossp for phase B (replaces memset) ----
    if (!phase) {
        if (blockIdx.x < 16)       counts[blockIdx.x * 256 + t] = 0.0f;
        else if (blockIdx.x == 16 && t < 256) lossp[t] = 0.0f;
    }

    // ---- prologue: stage A planes from x with on-the-fly fp16 split ----
    {
        int m = t >> 3, kb = (t & 7) * 32;
        float ssq0 = 0.0f, ssq1 = 0.0f;
#pragma unroll
        for (int rr = 0; rr < 2; ++rr) {
            int mm = m + 32 * rr;
            const float* src = x + (size_t)(row0 + mm) * DIM + kb;
            float ss = 0.0f;
#pragma unroll
            for (int g = 0; g < 4; ++g) {
                f32x4 f0 = __builtin_nontemporal_load((const f32x4*)(src + g * 8));
                f32x4 f1 = __builtin_nontemporal_load((const f32x4*)(src + g * 8 + 4));
                f16x8 h1, h2;
#pragma unroll
                for (int j = 0; j < 4; ++j) {
                    ss += f0[j] * f0[j] + f1[j] * f1[j];
                    _Float16 a = (_Float16)f0[j];
                    h1[j] = a; h2[j] = (_Float16)(f0[j] - (float)a);
                    _Float16 b = (_Float16)f1[j];
                    h1[j + 4] = b; h2[j + 4] = (_Float16)(f1[j] - (float)b);
                }
                int grp = ((kb >> 3) + g) ^ (mm & 7);
                *(f16x8*)&Ah[0][mm][grp * 8] = h1;
                *(f16x8*)&Ah[1][mm][grp * 8] = h2;
            }
            if (rr == 0) ssq0 = ss; else ssq1 = ss;
        }
        xsqp[m][t & 7]      = ssq0;
        xsqp[m + 32][t & 7] = ssq1;
    }
    __syncthreads();   // the ONLY barrier before the epilogue

    float best[16];
    int   bidx[16];
#pragma unroll
    for (int s = 0; s < 16; ++s) { best[s] = 3.4e38f; bidx[s] = 0x40000000; }

    // B fragment base: code-within-tile crow = w*64 + nf*16 + lo, d-off q*8
    const _Float16* ehp1 = ehs + (size_t)(w * 64 + lo) * 32 + q * 8;
    const _Float16* ehp2 = ehp1 + EH_PLANE;

    // register double-buffer for B fragments; parity = ks&1 (ks fully unrolled)
    f16x8 b1f[2][4], b2f[2][4];

    // prime: load B for so = ct0*8
    {
        const size_t so0 = (size_t)(ct0 * 8) * 8192;
#pragma unroll
        for (int nf = 0; nf < 4; ++nf) {
            b1f[0][nf] = *(const f16x8*)(ehp1 + so0 + nf * 512);
            b2f[0][nf] = *(const f16x8*)(ehp2 + so0 + nf * 512);
        }
    }

    for (int ct = ct0; ct < ct0 + 8; ++ct) {
        // prefetch this ct's e2 values (used only in the fold)
        float e2r[4];
#pragma unroll
        for (int nf = 0; nf < 4; ++nf)
            e2r[nf] = e2[ct * 256 + w * 64 + nf * 16 + lo];

        f32x4 acc[4][4];
#pragma unroll
        for (int mf = 0; mf < 4; ++mf)
#pragma unroll
            for (int nf = 0; nf < 4; ++nf) acc[mf][nf] = (f32x4)0.0f;

#pragma unroll
        for (int ks = 0; ks < 8; ++ks) {
            const int cur = ks & 1, nxt = cur ^ 1;
            const int so  = ct * 8 + ks;

            // ---- prefetch B for so+1 into the other parity buffer ----
            if (ks < 7 || ct < ct0 + 7) {
                const size_t po = (size_t)(so + 1) * 8192;
#pragma unroll
                for (int nf = 0; nf < 4; ++nf) {
                    b1f[nxt][nf] = *(const f16x8*)(ehp1 + po + nf * 512);
                    b2f[nxt][nf] = *(const f16x8*)(ehp2 + po + nf * 512);
                }
            }
            // pin the prefetch ahead of the MFMA cluster
            __builtin_amdgcn_sched_barrier(0);

            // ---- A fragments via LDS (conflict-free b128 via XOR swizzle) ----
            const int agrp = ((ks * 4 + q) ^ (lo & 7)) * 8;
            f16x8 a1[4], a2[4];
#pragma unroll
            for (int mf = 0; mf < 4; ++mf)
                a2[mf] = *(const f16x8*)&Ah[1][mf * 16 + lo][agrp];
#pragma unroll
            for (int mf = 0; mf < 4; ++mf)
                a1[mf] = *(const f16x8*)&Ah[0][mf * 16 + lo][agrp];

            // ---- MFMA cluster: per nf, product-major across mf (reuse dist 4) ----
#pragma unroll
            for (int nf = 0; nf < 4; ++nf) {
#pragma unroll
                for (int mf = 0; mf < 4; ++mf)
                    acc[mf][nf] = __builtin_amdgcn_mfma_f32_16x16x32_f16(a2[mf], b1f[cur][nf], acc[mf][nf], 0, 0, 0);
#pragma unroll
                for (int mf = 0; mf < 4; ++mf)
                    acc[mf][nf] = __builtin_amdgcn_mfma_f32_16x16x32_f16(a1[mf], b2f[cur][nf], acc[mf][nf], 0, 0, 0);
#pragma unroll
                for (int mf = 0; mf < 4; ++mf)
                    acc[mf][nf] = __builtin_amdgcn_mfma_f32_16x16x32_f16(a1[mf], b1f[cur][nf], acc[mf][nf], 0, 0, 0);
            }
        }

        // fold: dist = e2 - 2*score; exact lowest-index tie-break.
#pragma unroll
        for (int nf = 0; nf < 4; ++nf) {
            int ci = ct * 256 + w * 64 + nf * 16 + lo;
            float e2v = e2r[nf];
#pragma unroll
            for (int mf = 0; mf < 4; ++mf)
#pragma unroll
                for (int r = 0; r < 4; ++r) {
                    float dist = fmaf(-2.0f, acc[mf][nf][r], e2v);
                    int s = mf * 4 + r;
                    if (dist < best[s] || (dist == best[s] && ci < bidx[s])) {
                        best[s] = dist; bidx[s] = ci;
                    }
                }
        }
    }

    // ---- final argmin reduction (scratch overlays Ah) ----
    __syncthreads();
    float* rv = (float*)&Ah[0][0][0];                 // [64 rows][64 slots]
    int*   ri = (int*)(((char*)&Ah[0][0][0]) + 16384);
#pragma unroll
    for (int s = 0; s < 16; ++s) {
        int row = (s >> 2) * 16 + q * 4 + (s & 3);    // mf*16 + q*4 + r
        rv[row * 64 + w * 16 + lo] = best[s];
        ri[row * 64 + w * 16 + lo] = bidx[s];
    }
    __syncthreads();
    if (t < 64) {
        float bv; int bi;
        if (phase) { bv = carryV[row0 + t]; bi = carryI[row0 + t]; }
        else       { bv = 3.4e38f; bi = 0x40000000; }
        // staggered scan start -> conflict-free
        for (int jj = 0; jj < 64; ++jj) {
            int j = (jj + t) & 63;
            float v = rv[t * 64 + j];
            int  ii = ri[t * 64 + j];
            if (v < bv || (v == bv && ii < bi)) { bv = v; bi = ii; }
        }
        if (phase) {
            idx_out[row0 + t] = bi;
            out_idxf[row0 + t] = (float)bi;
            atomicAdd(&counts[bi], 1.0f);
            // loss_row = winning distance + ||x_row||^2 (validated round 13)
            float xsq = 0.0f;
#pragma unroll
            for (int j = 0; j < 8; ++j) xsq += xsqp[t][j];
            float lr = bv + xsq;
#pragma unroll
            for (int off = 32; off > 0; off >>= 1) lr += __shfl_down(lr, off, 64);
            if (t == 0) atomicAdd(&lossp[blockIdx.x & 255], lr);
        } else {
            carryV[row0 + t] = bv; carryI[row0 + t] = bi;
        }
    }
}

// merged: exclusive prefix sum over counts -> offs/woff  +  finalize
// (lossp is complete after argmin phase B)
__global__ void k_scanfin(const float* __restrict__ counts, const float* __restrict__ lossp,
                          const float* __restrict__ ema_counter,
                          const float* __restrict__ ema_cluster,
                          int* __restrict__ offs, int* __restrict__ woff,
                          float* __restrict__ cnorm, float* __restrict__ scal,
                          float* __restrict__ out)
{
    __shared__ int   ps[256];
    __shared__ float red[256];
    int t = threadIdx.x;

    // ---- scan ----
    int local[16];
    int s = 0;
#pragma unroll
    for (int j = 0; j < 16; ++j) {
        local[j] = s;
        s += (int)counts[t * 16 + j];
    }
    ps[t] = s;
    __syncthreads();
    for (int off = 1; off < 256; off <<= 1) {
        int v = (t >= off) ? ps[t - off] : 0;
        __syncthreads();
        ps[t] += v;
        __syncthreads();
    }
    int base = (t > 0) ? ps[t - 1] : 0;
#pragma unroll
    for (int j = 0; j < 16; ++j) {
        int o = base + local[j];
        offs[t * 16 + j] = o;
        woff[t * 16 + j] = o;
    }

    // ---- finalize ----
    float ls = lossp[t];
    float ent = 0.0f, casum = 0.0f;
    float ca[16];
#pragma unroll
    for (int j = 0; j < 16; ++j) {
        int k = j * 256 + t;
        float c = counts[k];
        float p = c * (1.0f / 32768.0f);
        ent += p * logf(p + 1e-10f);
        ca[j] = ema_cluster[k] * 0.99f + c * 0.01f;
        casum += ca[j];
    }
    __syncthreads();
    red[t] = ls; __syncthreads();
    for (int o = 128; o > 0; o >>= 1) { if (t < o) red[t] += red[t + o]; __syncthreads(); }
    float loss_tot = red[0]; __syncthreads();
    red[t] = ent; __syncthreads();
    for (int o = 128; o > 0; o >>= 1) { if (t < o) red[t] += red[t + o]; __syncthreads(); }
    float ent_tot = red[0]; __syncthreads();
    red[t] = casum; __syncthreads();
    for (int o = 128; o > 0; o >>= 1) { if (t < o) red[t] += red[t + o]; __syncthreads(); }
    float casum_tot = red[0]; __syncthreads();

    float bias = 1.0f - powf(0.99f, ema_counter[0] + 1.0f);
    float n = casum_tot / bias;
    float inv = n / (n + 4096.0f * 1e-5f);
#pragma unroll
    for (int j = 0; j < 16; ++j) {
        int k = j * 256 + t;
        cnorm[k] = (ca[j] / bias + 1e-5f) * inv;
    }
    if (t == 0) {
        out[OUT_LOSS] = 1.25f * loss_tot * (1.0f / (32768.0f * 256.0f));
        out[OUT_PERP] = expf(-ent_tot);
        scal[0] = bias;
    }
}

// rowlist[pos] = n, grouped by code (counting-sort scatter)
__global__ void k_scatter(const int* __restrict__ idx, int* __restrict__ woff,
                          int* __restrict__ rowlist)
{
    int n = blockIdx.x * 256 + threadIdx.x;
    int k = idx[n];
    int pos = atomicAdd(&woff[k], 1);
    rowlist[pos] = n;
}

// Per-code: dwT row (atomic-free) + out_q for every row in the bucket
__global__ void k_dw(const float* __restrict__ x, const unsigned short* __restrict__ ehs_,
                     const int* __restrict__ rowlist, const int* __restrict__ offs,
                     const float* __restrict__ counts, float* __restrict__ dwT,
                     float* __restrict__ out_q)
{
    __shared__ __align__(16) float es[256];
    __shared__ __align__(16) float red[4][256];
    const _Float16* ehs = (const _Float16*)ehs_;
    int k = blockIdx.x, t = threadIdx.x;
    int lane = t & 63, w = t >> 6;
    size_t base = (size_t)(((k >> 8) * 8) + (t >> 5)) * 8192 + (k & 255) * 32 + (t & 31);
    float e = (float)ehs[base] + (float)ehs[EH_PLANE + base];
    es[t] = e;
    int start = offs[k];
    int cnt   = (int)counts[k];
    __syncthreads();
    float4 ev = *(const float4*)&es[lane * 4];
    float4 acc = {0.0f, 0.0f, 0.0f, 0.0f};
    for (int j = w; j < cnt; j += 4) {
        int n = rowlist[start + j];
        float4 xv = *(const float4*)&x[(size_t)n * DIM + lane * 4];
        acc.x += xv.x; acc.y += xv.y; acc.z += xv.z; acc.w += xv.w;
        *(float4*)&out_q[(size_t)n * DIM + lane * 4] = ev;
    }
    *(float4*)&red[w][lane * 4] = acc;
    __syncthreads();
    float s = red[0][t] + red[1][t] + red[2][t] + red[3][t];
    dwT[(size_t)k * DIM + t] = s;
}

// new_embeddings[d][k] = (ema_dw*DECAY + dwT^T*(1-DECAY))/bias / cnorm[k]
__global__ void k_newemb(const float* __restrict__ dwT, const float* __restrict__ ema_dw,
                         const float* __restrict__ cnorm, const float* __restrict__ scal,
                         float* __restrict__ out_emb)
{
    __shared__ float tile[32][33];
    int t = threadIdx.x;
    int tx = t & 31, iy = t >> 5;
    int k0 = blockIdx.x * 32, d0 = blockIdx.y * 32;
#pragma unroll
    for (int j = 0; j < 4; ++j)
        tile[iy + 8 * j][tx] = dwT[(size_t)(k0 + iy + 8 * j) * DIM + d0 + tx];
    __syncthreads();
    float inv_bias = 1.0f / scal[0];
    float cn = cnorm[k0 + tx];
#pragma unroll
    for (int j = 0; j < 4; ++j) {
        int d = d0 + iy + 8 * j;
        float dwv = tile[tx][iy + 8 * j];
        float hid = ema_dw[(size_t)d * KCODE + k0 + tx] * 0.99f + dwv * 0.01f;
        out_emb[(size_t)d * KCODE + k0 + tx] = hid * inv_bias / cn;
    }
}

extern "C" void kernel_launch(void* const* d_in, const int* in_sizes, int n_in,
                              void* d_out, int out_size, void* d_ws, size_t ws_size,
                              hipStream_t stream)
{
    const float* x           = (const float*)d_in[0];
    const float* emb         = (const float*)d_in[1];
    const float* ema_counter = (const float*)d_in[2];
    const float* ema_cluster = (const float*)d_in[3];
    const float* ema_dw      = (const float*)d_in[4];
    float* out = (float*)d_out;
    float* ws  = (float*)d_ws;

    float* e2     = ws + WS_E2;
    float* counts = ws + WS_COUNTS;
    float* lossp  = ws + WS_LOSSP;
    float* scal   = ws + WS_SCAL;
    float* cnorm  = ws + WS_CNORM;
    int*   idxw   = (int*)(ws + WS_IDX);
    unsigned short* ehs = (unsigned short*)(ws + WS_EHS);
    float* dwT    = ws + WS_DWT;
    float* carryV = ws + WS_CARRYV;
    int*   carryI = (int*)(ws + WS_CARRYI);
    int*   rowlist= (int*)(ws + WS_CARRYV);   // overlays carryV (dead after argmin B)
    int*   offs   = (int*)(ws + WS_OFFS);
    int*   woff   = (int*)(ws + WS_WOFF);

    // 7 dispatches total (was 9): memset deleted (split_e writes e2 exactly;
    // argmin-A zeros counts/lossp), scan+finalize merged.
    k_split_e<<<128, 256, 0, stream>>>(emb, ehs, e2);
    k_argmin<<<512, 256, 0, stream>>>(x, ehs, e2, idxw, carryV, carryI,
                                      out + OUT_IDX, counts, lossp, 0, 0);
    k_argmin<<<512, 256, 0, stream>>>(x, ehs, e2, idxw, carryV, carryI,
                                      out + OUT_IDX, counts, lossp, 8, 1);
    k_scanfin<<<1, 256, 0, stream>>>(counts, lossp, ema_counter, ema_cluster,
                                     offs, woff, cnorm, scal, out);
    k_scatter<<<128, 256, 0, stream>>>(idxw, woff, rowlist);
    k_dw<<<4096, 256, 0, stream>>>(x, ehs, rowlist, offs, counts, dwT, out + OUT_Q);
    k_newemb<<<dim3(128, 8), 256, 0, stream>>>(dwT, ema_dw, cnorm, scal, out + OUT_EMB);
}

// Round 15
// 318.097 us; speedup vs baseline: 1.0513x; 1.0266x over previous
//
#include <hip/hip_runtime.h>
#include <math.h>

#define N_TOK 32768
#define DIM   256
#define KCODE 4096

// ---- workspace layout (float offsets) ----
#define WS_E2      0                      // [4096]
#define WS_COUNTS  4096                   // [4096]
#define WS_LOSSP   8192                   // [256]
#define WS_SCAL    8448                   // [64]  scal[0]=bias
#define WS_CNORM   8512                   // [4096]
#define WS_IDX     12608                  // int [32768]
#define WS_EHS     307520                 // fp16 planes [2][16][8][256][32] = 4 MB
#define WS_DWT     1356096                // dwT [4096*256]
#define WS_CARRYV  2404672                // float [32768] carry best value / later rowlist
#define WS_CARRYI  2437440                // int   [32768] carry best index
#define WS_OFFS    2470208                // int [4096] bucket starts
#define WS_WOFF    2474304                // int [4096] scatter cursors

// ---- output layout (float offsets) ----
#define OUT_Q      0
#define OUT_LOSS   8388608
#define OUT_PERP   8388609
#define OUT_IDX    8388610
#define OUT_EMB    8421378

#define EH_PLANE   1048576                // halves per eh plane

typedef _Float16 f16x8 __attribute__((ext_vector_type(8)));
typedef _Float16 f16x4 __attribute__((ext_vector_type(4)));
typedef float    f32x4 __attribute__((ext_vector_type(4)));

// emb [D][K] -> pre-tiled split planes ehs[p][ct][ks][code&255][d&31]
// 128 blocks, each owns 32 codes FULLY (loops all 8 d-tiles) -> e2[k]
// computed exactly in-block, written ONCE (no atomics, no memset needed).
// Verified passing in round 14.
__global__ void k_split_e(const float* __restrict__ emb, unsigned short* __restrict__ ehs_,
                          float* __restrict__ e2)
{
    __shared__ float tile[32][33];
    __shared__ float ssq_red[8][32];
    _Float16* ehs = (_Float16*)ehs_;
    int t  = threadIdx.x;
    int tx = t & 31, iy = t >> 5;
    int k0 = blockIdx.x * 32;
    float ssq = 0.0f;
    for (int dt = 0; dt < 8; ++dt) {
        int d0 = dt * 32;
        __syncthreads();   // protect tile reuse across iterations
#pragma unroll
        for (int j = 0; j < 4; ++j)
            tile[iy + 8 * j][tx] = emb[(size_t)(d0 + iy + 8 * j) * KCODE + k0 + tx];
        __syncthreads();
        int code = k0 + tx;
        size_t base = (size_t)(((code >> 8) * 8) + (d0 >> 5)) * 8192 + (code & 255) * 32 + iy * 4;
        f16x4 h1, h2;
#pragma unroll
        for (int j = 0; j < 4; ++j) {
            float v = tile[iy * 4 + j][tx];
            ssq += v * v;
            _Float16 a = (_Float16)v;
            h1[j] = a;
            h2[j] = (_Float16)(v - (float)a);
        }
        *(f16x4*)(ehs + base)            = h1;
        *(f16x4*)(ehs + EH_PLANE + base) = h2;
    }
    ssq_red[iy][tx] = ssq;
    __syncthreads();
    if (iy == 0) {
        float s = 0.0f;
#pragma unroll
        for (int j = 0; j < 8; ++j) s += ssq_red[j][tx];
        e2[k0 + tx] = s;
    }
}

// Argmin via fp16x2-split MFMA, two ct-half dispatches (2 MB L2 WS each).
// EXACT round-10 body — the best-measured configuration (100-102us, 124 VGPR,
// no spills, FETCH 25MB): f32-direct A staging, register-double-buffered B with
// sched_barrier pinning, per-nf product-major MFMA order, e2 prefetch, no
// setprio. Six schedule variants (dbuf depth, occupancy, issue order, setprio,
// block desync, threads/block) all plateaued at ~100us/45% MfmaUtil ->
// latency-structure-bound; body is frozen.
// Only addition vs round 10: phase A zeros counts/lossp (replaces the memset
// dispatch; dispatch boundary orders it before phase B / k_dw atomics).
__global__ __launch_bounds__(256, 2)
void k_argmin(const float* __restrict__ x, const unsigned short* __restrict__ ehs_,
              const float* __restrict__ e2, int* __restrict__ idx_out,
              float* __restrict__ carryV, int* __restrict__ carryI,
              float* __restrict__ out_idxf, float* __restrict__ counts,
              float* __restrict__ lossp, int ct0, int phase)
{
    __shared__ __align__(16) _Float16 Ah[2][64][256];   // 64 KB; XOR-swizzled 8-elem groups

    const _Float16* ehs = (const _Float16*)ehs_;

    const int t    = threadIdx.x;
    const int lane = t & 63, w = t >> 6;
    const int lo   = lane & 15, q = lane >> 4;
    const int row0 = blockIdx.x * 64;

    // ---- phase-A side duty: zero counts/lossp (replaces memset dispatch) ----
    if (!phase) {
        if (blockIdx.x < 16)  counts[blockIdx.x * 256 + t] = 0.0f;
        else if (blockIdx.x == 16) lossp[t] = 0.0f;
    }

    // ---- prologue: stage A planes from x with on-the-fly fp16 split ----
    {
        int m = t >> 3, kb = (t & 7) * 32;
#pragma unroll
        for (int rr = 0; rr < 2; ++rr) {
            int mm = m + 32 * rr;
            const float* src = x + (size_t)(row0 + mm) * DIM + kb;
#pragma unroll
            for (int g = 0; g < 4; ++g) {
                f32x4 f0 = __builtin_nontemporal_load((const f32x4*)(src + g * 8));
                f32x4 f1 = __builtin_nontemporal_load((const f32x4*)(src + g * 8 + 4));
                f16x8 h1, h2;
#pragma unroll
                for (int j = 0; j < 4; ++j) {
                    _Float16 a = (_Float16)f0[j];
                    h1[j] = a; h2[j] = (_Float16)(f0[j] - (float)a);
                    _Float16 b = (_Float16)f1[j];
                    h1[j + 4] = b; h2[j + 4] = (_Float16)(f1[j] - (float)b);
                }
                int grp = ((kb >> 3) + g) ^ (mm & 7);
                *(f16x8*)&Ah[0][mm][grp * 8] = h1;
                *(f16x8*)&Ah[1][mm][grp * 8] = h2;
            }
        }
    }
    __syncthreads();   // the ONLY barrier before the epilogue

    float best[16];
    int   bidx[16];
#pragma unroll
    for (int s = 0; s < 16; ++s) { best[s] = 3.4e38f; bidx[s] = 0; }

    // B fragment base: code-within-tile crow = w*64 + nf*16 + lo, d-off q*8
    const _Float16* ehp1 = ehs + (size_t)(w * 64 + lo) * 32 + q * 8;
    const _Float16* ehp2 = ehp1 + EH_PLANE;

    // register double-buffer for B fragments; parity = ks&1 (ks fully unrolled)
    f16x8 b1f[2][4], b2f[2][4];

    // prime: load B for so = ct0*8
    {
        const size_t so0 = (size_t)(ct0 * 8) * 8192;
#pragma unroll
        for (int nf = 0; nf < 4; ++nf) {
            b1f[0][nf] = *(const f16x8*)(ehp1 + so0 + nf * 512);
            b2f[0][nf] = *(const f16x8*)(ehp2 + so0 + nf * 512);
        }
    }

    for (int ct = ct0; ct < ct0 + 8; ++ct) {
        // prefetch this ct's e2 values (used only in the fold)
        float e2r[4];
#pragma unroll
        for (int nf = 0; nf < 4; ++nf)
            e2r[nf] = e2[ct * 256 + w * 64 + nf * 16 + lo];

        f32x4 acc[4][4];
#pragma unroll
        for (int mf = 0; mf < 4; ++mf)
#pragma unroll
            for (int nf = 0; nf < 4; ++nf) acc[mf][nf] = (f32x4)0.0f;

#pragma unroll
        for (int ks = 0; ks < 8; ++ks) {
            const int cur = ks & 1, nxt = cur ^ 1;
            const int so  = ct * 8 + ks;

            // ---- prefetch B for so+1 into the other parity buffer ----
            if (ks < 7 || ct < ct0 + 7) {
                const size_t po = (size_t)(so + 1) * 8192;
#pragma unroll
                for (int nf = 0; nf < 4; ++nf) {
                    b1f[nxt][nf] = *(const f16x8*)(ehp1 + po + nf * 512);
                    b2f[nxt][nf] = *(const f16x8*)(ehp2 + po + nf * 512);
                }
            }
            // pin the prefetch ahead of the MFMA cluster
            __builtin_amdgcn_sched_barrier(0);

            // ---- A fragments via LDS (conflict-free b128 via XOR swizzle) ----
            const int agrp = ((ks * 4 + q) ^ (lo & 7)) * 8;
            f16x8 a1[4], a2[4];
#pragma unroll
            for (int mf = 0; mf < 4; ++mf)
                a2[mf] = *(const f16x8*)&Ah[1][mf * 16 + lo][agrp];
#pragma unroll
            for (int mf = 0; mf < 4; ++mf)
                a1[mf] = *(const f16x8*)&Ah[0][mf * 16 + lo][agrp];

            // ---- MFMA cluster: per nf, product-major across mf (reuse dist 4) ----
#pragma unroll
            for (int nf = 0; nf < 4; ++nf) {
#pragma unroll
                for (int mf = 0; mf < 4; ++mf)
                    acc[mf][nf] = __builtin_amdgcn_mfma_f32_16x16x32_f16(a2[mf], b1f[cur][nf], acc[mf][nf], 0, 0, 0);
#pragma unroll
                for (int mf = 0; mf < 4; ++mf)
                    acc[mf][nf] = __builtin_amdgcn_mfma_f32_16x16x32_f16(a1[mf], b2f[cur][nf], acc[mf][nf], 0, 0, 0);
#pragma unroll
                for (int mf = 0; mf < 4; ++mf)
                    acc[mf][nf] = __builtin_amdgcn_mfma_f32_16x16x32_f16(a1[mf], b1f[cur][nf], acc[mf][nf], 0, 0, 0);
            }
        }

        // fold: dist = e2 - 2*score (x^2 row-constant dropped). codes ascending in ct,nf.
#pragma unroll
        for (int nf = 0; nf < 4; ++nf) {
            int cl = w * 64 + nf * 16 + lo;
            float e2v = e2r[nf];
#pragma unroll
            for (int mf = 0; mf < 4; ++mf)
#pragma unroll
                for (int r = 0; r < 4; ++r) {
                    float dist = fmaf(-2.0f, acc[mf][nf][r], e2v);
                    int s = mf * 4 + r;
                    if (dist < best[s]) { best[s] = dist; bidx[s] = ct * 256 + cl; }
                }
        }
    }

    // ---- final argmin reduction (scratch overlays Ah) ----
    __syncthreads();
    float* rv = (float*)&Ah[0][0][0];                 // [64 rows][64 slots]
    int*   ri = (int*)(((char*)&Ah[0][0][0]) + 16384);
#pragma unroll
    for (int s = 0; s < 16; ++s) {
        int row = (s >> 2) * 16 + q * 4 + (s & 3);    // mf*16 + q*4 + r
        rv[row * 64 + w * 16 + lo] = best[s];
        ri[row * 64 + w * 16 + lo] = bidx[s];
    }
    __syncthreads();
    if (t < 64) {
        float bv; int bi;
        if (phase) { bv = carryV[row0 + t]; bi = carryI[row0 + t]; }
        else       { bv = 3.4e38f; bi = 0x40000000; }
        // staggered scan start -> conflict-free
        for (int jj = 0; jj < 64; ++jj) {
            int j = (jj + t) & 63;
            float v = rv[t * 64 + j];
            int  ii = ri[t * 64 + j];
            if (v < bv || (v == bv && ii < bi)) { bv = v; bi = ii; }
        }
        if (phase) {
            idx_out[row0 + t] = bi;
            out_idxf[row0 + t] = (float)bi;
            atomicAdd(&counts[bi], 1.0f);
        } else {
            carryV[row0 + t] = bv; carryI[row0 + t] = bi;
        }
    }
}

// exclusive prefix sum over counts[4096] -> offs, woff (one block, 256 threads x 16)
__global__ void k_scan(const float* __restrict__ counts, int* __restrict__ offs,
                       int* __restrict__ woff)
{
    __shared__ int ps[256];
    int t = threadIdx.x;
    int local[16];
    int s = 0;
#pragma unroll
    for (int j = 0; j < 16; ++j) {
        local[j] = s;
        s += (int)counts[t * 16 + j];
    }
    ps[t] = s;
    __syncthreads();
    for (int off = 1; off < 256; off <<= 1) {
        int v = (t >= off) ? ps[t - off] : 0;
        __syncthreads();
        ps[t] += v;
        __syncthreads();
    }
    int base = (t > 0) ? ps[t - 1] : 0;
#pragma unroll
    for (int j = 0; j < 16; ++j) {
        int o = base + local[j];
        offs[t * 16 + j] = o;
        woff[t * 16 + j] = o;
    }
}

// rowlist[pos] = n, grouped by code (counting-sort scatter)
__global__ void k_scatter(const int* __restrict__ idx, int* __restrict__ woff,
                          int* __restrict__ rowlist)
{
    int n = blockIdx.x * 256 + threadIdx.x;
    int k = idx[n];
    int pos = atomicAdd(&woff[k], 1);
    rowlist[pos] = n;
}

// Per-code fused update: one block per code k.
//   dwT[k][:]  = sum of x rows in bucket k          (atomic-free)
//   out_q[n,:] = e_k  for every row n in bucket
//   lossp     += cnt*|e|^2 - 2*e.dw + sum|x|^2      (algebraic bucket loss)
__global__ void k_dw(const float* __restrict__ x, const unsigned short* __restrict__ ehs_,
                     const int* __restrict__ rowlist, const int* __restrict__ offs,
                     const float* __restrict__ counts, float* __restrict__ dwT,
                     float* __restrict__ out_q, float* __restrict__ lossp)
{
    __shared__ __align__(16) float es[256];
    __shared__ __align__(16) float red[4][256];
    const _Float16* ehs = (const _Float16*)ehs_;
    int k = blockIdx.x, t = threadIdx.x;
    int lane = t & 63, w = t >> 6;
    size_t base = (size_t)(((k >> 8) * 8) + (t >> 5)) * 8192 + (k & 255) * 32 + (t & 31);
    float e = (float)ehs[base] + (float)ehs[EH_PLANE + base];
    es[t] = e;
    int start = offs[k];
    int cnt   = (int)counts[k];
    __syncthreads();
    float4 ev = *(const float4*)&es[lane * 4];
    float4 acc = {0.0f, 0.0f, 0.0f, 0.0f};
    float sq = 0.0f;
    for (int j = w; j < cnt; j += 4) {
        int n = rowlist[start + j];
        float4 xv = *(const float4*)&x[(size_t)n * DIM + lane * 4];
        acc.x += xv.x; acc.y += xv.y; acc.z += xv.z; acc.w += xv.w;
        sq += xv.x * xv.x + xv.y * xv.y + xv.z * xv.z + xv.w * xv.w;
        *(float4*)&out_q[(size_t)n * DIM + lane * 4] = ev;
    }
    *(float4*)&red[w][lane * 4] = acc;
    __syncthreads();
    float s = red[0][t] + red[1][t] + red[2][t] + red[3][t];
    dwT[(size_t)k * DIM + t] = s;
    float v1 = es[t] * s;
    float v2 = e * e;
    float v3 = sq;
#pragma unroll
    for (int off = 32; off > 0; off >>= 1) {
        v1 += __shfl_down(v1, off, 64);
        v2 += __shfl_down(v2, off, 64);
        v3 += __shfl_down(v3, off, 64);
    }
    __syncthreads();
    if (lane == 0) { red[0][w] = v1; red[1][w] = v2; red[2][w] = v3; }
    __syncthreads();
    if (t == 0 && cnt > 0) {
        float dot = red[0][0] + red[0][1] + red[0][2] + red[0][3];
        float e2t = red[1][0] + red[1][1] + red[1][2] + red[1][3];
        float sqt = red[2][0] + red[2][1] + red[2][2] + red[2][3];
        atomicAdd(&lossp[k & 255], (float)cnt * e2t - 2.0f * dot + sqt);
    }
}

__global__ void k_finalize(const float* __restrict__ counts, const float* __restrict__ lossp,
                           const float* __restrict__ ema_counter,
                           const float* __restrict__ ema_cluster,
                           float* __restrict__ cnorm, float* __restrict__ scal,
                           float* __restrict__ out)
{
    __shared__ float red[256];
    int t = threadIdx.x;
    float ls = lossp[t];
    float ent = 0.0f, casum = 0.0f;
    float ca[16];
#pragma unroll
    for (int j = 0; j < 16; ++j) {
        int k = j * 256 + t;
        float c = counts[k];
        float p = c * (1.0f / 32768.0f);
        ent += p * logf(p + 1e-10f);
        ca[j] = ema_cluster[k] * 0.99f + c * 0.01f;
        casum += ca[j];
    }
    red[t] = ls; __syncthreads();
    for (int o = 128; o > 0; o >>= 1) { if (t < o) red[t] += red[t + o]; __syncthreads(); }
    float loss_tot = red[0]; __syncthreads();
    red[t] = ent; __syncthreads();
    for (int o = 128; o > 0; o >>= 1) { if (t < o) red[t] += red[t + o]; __syncthreads(); }
    float ent_tot = red[0]; __syncthreads();
    red[t] = casum; __syncthreads();
    for (int o = 128; o > 0; o >>= 1) { if (t < o) red[t] += red[t + o]; __syncthreads(); }
    float casum_tot = red[0]; __syncthreads();

    float bias = 1.0f - powf(0.99f, ema_counter[0] + 1.0f);
    float n = casum_tot / bias;
    float inv = n / (n + 4096.0f * 1e-5f);
#pragma unroll
    for (int j = 0; j < 16; ++j) {
        int k = j * 256 + t;
        cnorm[k] = (ca[j] / bias + 1e-5f) * inv;
    }
    if (t == 0) {
        out[OUT_LOSS] = 1.25f * loss_tot * (1.0f / (32768.0f * 256.0f));
        out[OUT_PERP] = expf(-ent_tot);
        scal[0] = bias;
    }
}

// new_embeddings[d][k] = (ema_dw*DECAY + dwT^T*(1-DECAY))/bias / cnorm[k]
__global__ void k_newemb(const float* __restrict__ dwT, const float* __restrict__ ema_dw,
                         const float* __restrict__ cnorm, const float* __restrict__ scal,
                         float* __restrict__ out_emb)
{
    __shared__ float tile[32][33];
    int t = threadIdx.x;
    int tx = t & 31, iy = t >> 5;
    int k0 = blockIdx.x * 32, d0 = blockIdx.y * 32;
#pragma unroll
    for (int j = 0; j < 4; ++j)
        tile[iy + 8 * j][tx] = dwT[(size_t)(k0 + iy + 8 * j) * DIM + d0 + tx];
    __syncthreads();
    float inv_bias = 1.0f / scal[0];
    float cn = cnorm[k0 + tx];
#pragma unroll
    for (int j = 0; j < 4; ++j) {
        int d = d0 + iy + 8 * j;
        float dwv = tile[tx][iy + 8 * j];
        float hid = ema_dw[(size_t)d * KCODE + k0 + tx] * 0.99f + dwv * 0.01f;
        out_emb[(size_t)d * KCODE + k0 + tx] = hid * inv_bias / cn;
    }
}

extern "C" void kernel_launch(void* const* d_in, const int* in_sizes, int n_in,
                              void* d_out, int out_size, void* d_ws, size_t ws_size,
                              hipStream_t stream)
{
    const float* x           = (const float*)d_in[0];
    const float* emb         = (const float*)d_in[1];
    const float* ema_counter = (const float*)d_in[2];
    const float* ema_cluster = (const float*)d_in[3];
    const float* ema_dw      = (const float*)d_in[4];
    float* out = (float*)d_out;
    float* ws  = (float*)d_ws;

    float* e2     = ws + WS_E2;
    float* counts = ws + WS_COUNTS;
    float* lossp  = ws + WS_LOSSP;
    float* scal   = ws + WS_SCAL;
    float* cnorm  = ws + WS_CNORM;
    int*   idxw   = (int*)(ws + WS_IDX);
    unsigned short* ehs = (unsigned short*)(ws + WS_EHS);
    float* dwT    = ws + WS_DWT;
    float* carryV = ws + WS_CARRYV;
    int*   carryI = (int*)(ws + WS_CARRYI);
    int*   rowlist= (int*)(ws + WS_CARRYV);   // overlays carryV (dead after argmin B)
    int*   offs   = (int*)(ws + WS_OFFS);
    int*   woff   = (int*)(ws + WS_WOFF);

    // 8 dispatches: memset eliminated (split_e writes e2 exactly; argmin-A
    // zeros counts/lossp). Argmin body = round-10 best-measured config.
    k_split_e<<<128, 256, 0, stream>>>(emb, ehs, e2);
    k_argmin<<<512, 256, 0, stream>>>(x, ehs, e2, idxw, carryV, carryI,
                                      out + OUT_IDX, counts, lossp, 0, 0);
    k_argmin<<<512, 256, 0, stream>>>(x, ehs, e2, idxw, carryV, carryI,
                                      out + OUT_IDX, counts, lossp, 8, 1);
    k_scan<<<1, 256, 0, stream>>>(counts, offs, woff);
    k_scatter<<<128, 256, 0, stream>>>(idxw, woff, rowlist);
    k_dw<<<4096, 256, 0, stream>>>(x, ehs, rowlist, offs, counts, dwT,
                                   out + OUT_Q, lossp);
    k_finalize<<<1, 256, 0, stream>>>(counts, lossp, ema_counter, ema_cluster,
                                      cnorm, scal, out);
    k_newemb<<<dim3(128, 8), 256, 0, stream>>>(dwT, ema_dw, cnorm, scal, out + OUT_EMB);
}